// Round 1
// 735.538 us; speedup vs baseline: 1.1055x; 1.1055x over previous
//
#include <hip/hip_runtime.h>

// Problem: relu(quant8(x) @ quant8(W)^T + bias)
//   x: [2,2048,4096] f32  -> M=4096, K=4096
//   W: [16384,4096]  f32  -> N=16384 (row-major in K, i.e. B^T layout)
//   out: [2,2048,16384] f32
//
// R2 change: port the GEMM from the m97-style 128x128 / 2-barrier structure
// (measured ceiling ~35% of i8 peak) to the 256x256 8-phase schedule
// (T3+T4 counted-vmcnt + T5 setprio), i8-isomorphic to the verified bf16
// template: BK=128 i8 bytes == BK=64 bf16 bytes, identical staging geometry.
//
// Schedule (group = 4 phases = one K-tile, 2 K-tiles unrolled per loop iter):
//   phase 1 q(A0,B0): read A0(8xb128)+B0(4xb128); stage (T+1)-B0 -> other buf
//   phase 2 q(A0,B1): read B1;                    stage (T+2)-A0 -> cur buf
//   phase 3 q(A1,B1): read A1;                    stage (T+2)-B1 -> cur buf
//   phase 4 q(A1,B0): read B0;                    stage (T+2)-A1 -> cur buf
//                      s_waitcnt vmcnt(6)  <- never 0 in main loop
//   each phase: barrier; lgkmcnt(0); setprio(1); 16 MFMA; setprio(0); barrier
// Region-retirement makes the T+2 stages race-free: A0 last read ph1, B1 ph2,
// A1 ph3, B0 ph4; each stage lands one phase after its region retires, and
// raw s_barrier (no implicit vmcnt drain) separates read-complete from issue.
// vmcnt(6) at ph4 covers stages through ph1 => tile T+1 fully in LDS before
// its first read at ph5.
//
// LDS swizzle (R1, bank-conflict=0) kept: physical 16B-chunk p of row r holds
// logical chunk p ^ (r&7); staging pre-swizzles the per-lane GLOBAL column
// (global_load_lds LDS dest must stay linear base + lane*16).

#define HIDDEN 4096
#define INTER 16384
#define MDIM 4096
#define BK 128
#define NT (HIDDEN / BK)   // 32 K-tiles

typedef int v4i __attribute__((ext_vector_type(4)));

// ---------------------------------------------------------------------------
// Quantize: q = round_ne(clamp(x, -c, c) * 127/c), packed 4 int8 per int32.
// ---------------------------------------------------------------------------
__global__ __launch_bounds__(256) void quantize_kernel(
    const float* __restrict__ x,
    signed char* __restrict__ q,
    const float* __restrict__ clip_ptr,
    int n4)
{
    int i = blockIdx.x * blockDim.x + threadIdx.x;
    if (i >= n4) return;
    float c = fabsf(clip_ptr[0]);
    float inv_scale = 127.0f / c;
    float4 v = reinterpret_cast<const float4*>(x)[i];
    int q0 = __float2int_rn(fminf(fmaxf(v.x, -c), c) * inv_scale);
    int q1 = __float2int_rn(fminf(fmaxf(v.y, -c), c) * inv_scale);
    int q2 = __float2int_rn(fminf(fmaxf(v.z, -c), c) * inv_scale);
    int q3 = __float2int_rn(fminf(fmaxf(v.w, -c), c) * inv_scale);
    int pack = (q0 & 0xff) | ((q1 & 0xff) << 8) | ((q2 & 0xff) << 16) | (q3 << 24);
    reinterpret_cast<int*>(q)[i] = pack;
}

// ---------------------------------------------------------------------------
// i8 GEMM, 256x256 tile, 512 threads = 8 waves (2M x 4N), 8-phase schedule.
// Per wave: 128 M-rows x 64 N-cols as 2(qm) x 2(qn) x 4(m) x 2(n) 16x16 frags.
// ---------------------------------------------------------------------------

#define GLL(src, dst) __builtin_amdgcn_global_load_lds( \
    (const __attribute__((address_space(1))) void*)(src), \
    (__attribute__((address_space(3))) void*)(dst), 16, 0, 0)

// one half-tile = 128 rows x 128 B = 2 issues of (512 threads x 16 B)
#define STAGE(gptr, lptr) do { \
    GLL((gptr), (lptr)); \
    GLL((gptr) + (size_t)64 * HIDDEN, (lptr) + 8192); } while (0)

#define BARX() __builtin_amdgcn_s_barrier()
#define LGKM0() asm volatile("s_waitcnt lgkmcnt(0)" ::: "memory")
#define VM6() asm volatile("s_waitcnt vmcnt(6)" ::: "memory")
#define VM4() asm volatile("s_waitcnt vmcnt(4)" ::: "memory")
#define VM0() asm volatile("s_waitcnt vmcnt(0)" ::: "memory")
#define VMNOP()
#define PRIO1() __builtin_amdgcn_s_setprio(1)
#define PRIO0() __builtin_amdgcn_s_setprio(0)

#define READ_A(cb, qm) do { _Pragma("unroll") \
    for (int m_ = 0; m_ < 4; m_++) { \
      const signed char* p_ = &As[cb][(qm) * 16384 + aOff + m_ * 2048]; \
      a[m_][0] = *reinterpret_cast<const v4i*>(p_ + c0); \
      a[m_][1] = *reinterpret_cast<const v4i*>(p_ + c1); } } while (0)

#define READ_B(cb, qn) do { _Pragma("unroll") \
    for (int n_ = 0; n_ < 2; n_++) { \
      const signed char* p_ = &Bs[cb][(qn) * 16384 + bOff + n_ * 2048]; \
      b[n_][0] = *reinterpret_cast<const v4i*>(p_ + c0); \
      b[n_][1] = *reinterpret_cast<const v4i*>(p_ + c1); } } while (0)

#define MFMA_Q(qm, qn) do { _Pragma("unroll") \
    for (int m_ = 0; m_ < 4; m_++) { _Pragma("unroll") \
      for (int n_ = 0; n_ < 2; n_++) { \
        acc[qm][qn][m_][n_] = __builtin_amdgcn_mfma_i32_16x16x64_i8( \
            a[m_][0], b[n_][0], acc[qm][qn][m_][n_], 0, 0, 0); \
        acc[qm][qn][m_][n_] = __builtin_amdgcn_mfma_i32_16x16x64_i8( \
            a[m_][1], b[n_][1], acc[qm][qn][m_][n_], 0, 0, 0); } } } while (0)

// One K-tile group. cb = buffer of tile T, ob = the other buffer.
// SN: stage (T+1)-B0 at ph1.  S2: stage (T+2) {A0,B1,A1} at ph2-4.
#define GROUP(cb, ob, T, SN, S2, VMW) do { \
    /* ph1: q(0,0) -- A0 region retires here */ \
    READ_A(cb, 0); READ_B(cb, 0); \
    if (SN) STAGE(gB + (size_t)((T) + 1) * BK, &Bs[ob][0] + ldsT); \
    BARX(); LGKM0(); PRIO1(); MFMA_Q(0, 0); PRIO0(); BARX(); \
    /* ph2: q(0,1) -- B1 retires; overwrite retired A0 with (T+2)-A0 */ \
    READ_B(cb, 1); \
    if (S2) STAGE(gA + (size_t)((T) + 2) * BK, &As[cb][0] + ldsT); \
    BARX(); LGKM0(); PRIO1(); MFMA_Q(0, 1); PRIO0(); BARX(); \
    /* ph3: q(1,1) -- A1 retires; overwrite retired B1 */ \
    READ_A(cb, 1); \
    if (S2) STAGE(gB + (size_t)128 * HIDDEN + (size_t)((T) + 2) * BK, &Bs[cb][16384] + ldsT); \
    BARX(); LGKM0(); PRIO1(); MFMA_Q(1, 1); PRIO0(); BARX(); \
    /* ph4: q(1,0) -- re-read B0; overwrite retired A1; counted vmcnt */ \
    READ_B(cb, 0); \
    if (S2) STAGE(gA + (size_t)128 * HIDDEN + (size_t)((T) + 2) * BK, &As[cb][16384] + ldsT); \
    VMW(); \
    BARX(); LGKM0(); PRIO1(); MFMA_Q(1, 0); PRIO0(); BARX(); \
  } while (0)

__global__ __launch_bounds__(512, 2) void gemm_i8_kernel(
    const signed char* __restrict__ qA,   // [MDIM, HIDDEN]
    const signed char* __restrict__ qB,   // [INTER, HIDDEN]
    const float* __restrict__ bias,       // [INTER]
    const float* __restrict__ wclip,
    const float* __restrict__ iclip,
    float* __restrict__ out)              // [MDIM, INTER]
{
    // [buf][256 rows][128 B], double-buffered: 4 x 32 KiB = 128 KiB
    __shared__ __align__(16) signed char As[2][32768];
    __shared__ __align__(16) signed char Bs[2][32768];

    const int t = threadIdx.x;
    const int L = t & 63;
    const int W = t >> 6;          // wave 0..7
    const int wm = W >> 2;         // 0..1
    const int wn = W & 3;          // 0..3
    const int lane16 = L & 15;
    const int quad = L >> 4;
    const int swz = lane16 & 7;

    // XCD-aware bijective swizzle (nwg = 1024, 1024 % 8 == 0)
    int wg = blockIdx.y * 64 + blockIdx.x;
    wg = (wg & 7) * 128 + (wg >> 3);
    const int mBase = (wg >> 6) * 256;
    const int nBase = (wg & 63) * 256;

    // Staging: thread t covers row (t>>3), physical chunk (t&7) of a half-tile.
    // Source column pre-swizzled: logical chunk = (t&7) ^ (row&7).
    const int sRow = t >> 3;                         // 0..63
    const int sColSwz = ((t & 7) ^ (sRow & 7)) * 16;
    const signed char* gA = qA + (size_t)(mBase + sRow) * HIDDEN + sColSwz;
    const signed char* gB = qB + (size_t)(nBase + sRow) * HIDDEN + sColSwz;
    const int ldsT = t * 16;

    // Fragment read offsets (row & 7 == lane16 & 7 for every fragment row).
    const int aOff = (wm * 64 + lane16) * 128;
    const int bOff = (wn * 32 + lane16) * 128;
    const int c0 = (quad ^ swz) * 16;
    const int c1 = ((quad + 4) ^ swz) * 16;

    v4i acc[2][2][4][2];
#pragma unroll
    for (int i = 0; i < 2; i++)
#pragma unroll
        for (int j = 0; j < 2; j++)
#pragma unroll
            for (int m = 0; m < 4; m++)
#pragma unroll
                for (int n = 0; n < 2; n++)
                    acc[i][j][m][n] = (v4i){0, 0, 0, 0};

    v4i a[4][2], b[2][2];

    // Prologue: tile0 {A0,B0,A1,B1}; tile1 {A0,B1,A1}; tile1-B0 comes at
    // group0.ph1. vmcnt(6) => tile0 complete, 3 half-tiles in flight.
    STAGE(gA, &As[0][0] + ldsT);                                   // t0-A0
    STAGE(gB, &Bs[0][0] + ldsT);                                   // t0-B0
    STAGE(gA + (size_t)128 * HIDDEN, &As[0][16384] + ldsT);        // t0-A1
    STAGE(gB + (size_t)128 * HIDDEN, &Bs[0][16384] + ldsT);        // t0-B1
    VM4();
    STAGE(gA + BK, &As[1][0] + ldsT);                              // t1-A0
    STAGE(gB + (size_t)128 * HIDDEN + BK, &Bs[1][16384] + ldsT);   // t1-B1
    STAGE(gA + (size_t)128 * HIDDEN + BK, &As[1][16384] + ldsT);   // t1-A1
    VM6();
    BARX();

    // Main loop: groups 0..29 fully pipelined (vmcnt never drained).
    for (int T = 0; T < NT - 2; T += 2) {
        GROUP(0, 1, T,     1, 1, VM6);
        GROUP(1, 0, T + 1, 1, 1, VM6);
    }
    // Epilogue groups: stage t31-B0, then drain once; last tile plain.
    GROUP(0, 1, NT - 2, 1, 0, VM0);
    GROUP(1, 0, NT - 1, 0, 0, VMNOP);

    // Epilogue: out = relu(acc * (|wc|/127)*(|ic|/127) + bias)
    const float scale = (fabsf(wclip[0]) / 127.0f) * (fabsf(iclip[0]) / 127.0f);

    float bv[2][2];
#pragma unroll
    for (int qn = 0; qn < 2; qn++)
#pragma unroll
        for (int n = 0; n < 2; n++)
            bv[qn][n] = bias[nBase + qn * 128 + wn * 32 + n * 16 + lane16];

    // C/D mapping (guide-verified, dtype-independent): col = lane&15,
    // row = quad*4 + reg.
#pragma unroll
    for (int qm = 0; qm < 2; qm++)
#pragma unroll
        for (int m = 0; m < 4; m++)
#pragma unroll
            for (int r = 0; r < 4; r++) {
                const int row = mBase + qm * 128 + wm * 64 + m * 16 + quad * 4 + r;
                float* orow = out + (size_t)row * INTER + nBase + wn * 32 + lane16;
#pragma unroll
                for (int qn = 0; qn < 2; qn++)
#pragma unroll
                    for (int n = 0; n < 2; n++) {
                        float v = (float)acc[qm][qn][m][n][r] * scale + bv[qn][n];
                        orow[qn * 128 + n * 16] = fmaxf(v, 0.0f);
                    }
            }
}

extern "C" void kernel_launch(void* const* d_in, const int* in_sizes, int n_in,
                              void* d_out, int out_size, void* d_ws, size_t ws_size,
                              hipStream_t stream) {
    const float* hidden_states  = (const float*)d_in[0];  // [2,2048,4096]
    const float* weight         = (const float*)d_in[1];  // [16384,4096]
    const float* bias           = (const float*)d_in[2];  // [16384]
    const float* weight_clip    = (const float*)d_in[3];  // scalar
    const float* input_clip     = (const float*)d_in[4];  // scalar
    float* out = (float*)d_out;

    signed char* qA = (signed char*)d_ws;                         // 16 MiB
    signed char* qB = qA + (size_t)MDIM * HIDDEN;                 // 64 MiB

    // Quantize activations: 4096*4096 / 4 elems per thread
    {
        int n4 = MDIM * HIDDEN / 4;
        quantize_kernel<<<n4 / 256, 256, 0, stream>>>(hidden_states, qA, input_clip, n4);
    }
    // Quantize weights: 16384*4096 / 4
    {
        int n4 = INTER * HIDDEN / 4;
        quantize_kernel<<<n4 / 256, 256, 0, stream>>>(weight, qB, weight_clip, n4);
    }

    dim3 grid(INTER / 256, MDIM / 256);   // 64 x 16 = 1024 blocks
    gemm_i8_kernel<<<grid, 512, 0, stream>>>(qA, qB, bias, weight_clip, input_clip, out);
}